// Round 1
// baseline (178.255 us; speedup 1.0000x reference)
//
#include <hip/hip_runtime.h>

typedef _Float16 h16x8 __attribute__((ext_vector_type(8)));
typedef _Float16 h16x4 __attribute__((ext_vector_type(4)));
typedef float    fx4   __attribute__((ext_vector_type(4)));

static __device__ __forceinline__ fx4 mfma16(h16x8 a, h16x8 b, fx4 c) {
  return __builtin_amdgcn_mfma_f32_16x16x32_f16(a, b, c, 0, 0, 0);
}

// Feature permutation for the C-layout -> A-layout LDS transpose:
// writer (lane c, col-tile ct) stores feature f=16*ct+c at position p = 4*c+ct
// (so the 4 ct values pack into one ds_write_b64). Reader consumes positions
// contiguously; the NEXT layer's weight rows are loaded with f = 16*(p&3)+(p>>2)
// so the K-order matches (dot products are order-invariant).

__global__ __launch_bounds__(256, 2)
void deepset_kernel(const float* __restrict__ x,   const float* __restrict__ vel,
                    const float* __restrict__ pW1, const float* __restrict__ pb1,
                    const float* __restrict__ pW2, const float* __restrict__ pb2,
                    const float* __restrict__ pW3, const float* __restrict__ pb3,
                    const float* __restrict__ rW1, const float* __restrict__ rb1,
                    const float* __restrict__ rW2, const float* __restrict__ rb2,
                    const float* __restrict__ rW3, const float* __restrict__ rb3,
                    float* __restrict__ out)
{
  // wave-private transpose tiles (stride 72 halves = 144 B: 8B/16B aligned rows,
  // breaks the 128B power-of-2 bank stride)
  __shared__ __align__(16) _Float16 h2T[4][16][72];
  __shared__ __align__(16) _Float16 Xlds[64][72];

  const int tid  = threadIdx.x;
  const int wave = tid >> 6;
  const int lane = tid & 63;
  const int q    = lane >> 4;   // quad
  const int c    = lane & 15;

  // ---- phi W2/W3 B-fragments: lane holds W[k = 32*ks + 8*q + j][n = 16*ct + c]
  h16x8 B2[4][2], B3[4][2];
#pragma unroll
  for (int ct = 0; ct < 4; ++ct)
#pragma unroll
    for (int ks = 0; ks < 2; ++ks) {
      h16x8 f2, f3;
#pragma unroll
      for (int j = 0; j < 8; ++j) {
        const int p = 32*ks + 8*q + j;
        f2[j] = (_Float16)pW2[p*64 + 16*ct + c];
        const int f = 16*(p & 3) + (p >> 2);          // permuted row for W3
        f3[j] = (_Float16)pW3[f*64 + 16*ct + c];
      }
      B2[ct][ks] = f2;
      B3[ct][ks] = f3;
    }
  float b2v[4], b3v[4];
#pragma unroll
  for (int ct = 0; ct < 4; ++ct) { b2v[ct] = pb2[16*ct + c]; b3v[ct] = pb3[16*ct + c]; }

  // W1 rows 0,1 (obs.x, obs.y coefficients) for this lane's 16 k-features
  float w0[2][8], w1[2][8];
#pragma unroll
  for (int ks = 0; ks < 2; ++ks)
#pragma unroll
    for (int j = 0; j < 8; ++j) {
      const int f = 32*ks + 8*q + j;
      w0[ks][j] = pW1[0*64 + f];
      w1[ks][j] = pW1[1*64 + f];
    }

  const int sBaseBlock = blockIdx.x * 64;
  const int sBase = sBaseBlock + wave * 16;

  // ================= phi + pool: 16 states per wave =================
#pragma unroll 1
  for (int si = 0; si < 16; ++si) {
    const int sg = sBase + si;
    const float2 v2 = *(const float2*)(vel + 2*(size_t)sg);
    // per-state constant part of layer 1: vel.x*W1[2] + vel.y*W1[3] + b1
    float vb[2][8];
#pragma unroll
    for (int ks = 0; ks < 2; ++ks)
#pragma unroll
      for (int j = 0; j < 8; ++j) {
        const int f = 32*ks + 8*q + j;
        vb[ks][j] = fmaf(v2.x, pW1[128 + f], fmaf(v2.y, pW1[192 + f], pb1[f]));
      }

    float Xacc[4] = {0.f, 0.f, 0.f, 0.f};
#pragma unroll 1
    for (int hh = 0; hh < 2; ++hh) {          // two 16-obstacle tiles per state
      const int o = 16*hh + c;
      const float2 ob = *(const float2*)(x + (size_t)sg*64 + 2*o);
      // layer 1 straight into A-fragment layout: lane holds h1[m=c][k=32ks+8q+j]
      h16x8 A1[2];
#pragma unroll
      for (int ks = 0; ks < 2; ++ks) {
        h16x8 a;
#pragma unroll
        for (int j = 0; j < 8; ++j) {
          const float h = fmaf(ob.x, w0[ks][j], fmaf(ob.y, w1[ks][j], vb[ks][j]));
          a[j] = (_Float16)fmaxf(h, 0.f);
        }
        A1[ks] = a;
      }
      // layer 2: 16x64 = 4 col-tiles x (K=64 -> 2 mfma)
      fx4 C2[4];
#pragma unroll
      for (int ct = 0; ct < 4; ++ct) {
        fx4 acc = {0.f, 0.f, 0.f, 0.f};
        acc = mfma16(A1[0], B2[ct][0], acc);
        acc = mfma16(A1[1], B2[ct][1], acc);
        C2[ct] = acc;
      }
      // bias+relu, permuted transpose write (4x ds_write_b64 per lane)
#pragma unroll
      for (int r = 0; r < 4; ++r) {
        h16x4 pk;
#pragma unroll
        for (int ct = 0; ct < 4; ++ct)
          pk[ct] = (_Float16)fmaxf(C2[ct][r] + b2v[ct], 0.f);
        *(h16x4*)&h2T[wave][4*q + r][4*c] = pk;
      }
      __builtin_amdgcn_s_waitcnt(0xC07F);      // lgkmcnt(0) only
      __builtin_amdgcn_wave_barrier();
      h16x8 A3[2];
#pragma unroll
      for (int ks = 0; ks < 2; ++ks)
        A3[ks] = *(const h16x8*)&h2T[wave][c][32*ks + 8*q];
      __builtin_amdgcn_wave_barrier();
      // layer 3 (linear; B3 rows already permuted to match storage order)
      fx4 C3[4];
#pragma unroll
      for (int ct = 0; ct < 4; ++ct) {
        fx4 acc = {0.f, 0.f, 0.f, 0.f};
        acc = mfma16(A3[0], B3[ct][0], acc);
        acc = mfma16(A3[1], B3[ct][1], acc);
        C3[ct] = acc;
      }
      // pool the 16 rows of this tile: 4 regs (rows 4q..4q+3) then cross-quad
#pragma unroll
      for (int ct = 0; ct < 4; ++ct) {
        float v = (C3[ct][0] + C3[ct][1]) + (C3[ct][2] + C3[ct][3]) + 4.f*b3v[ct];
        v += __shfl_down(v, 16);
        v += __shfl_down(v, 32);
        Xacc[ct] += v;                          // valid in lanes 0..15
      }
    }
    if (lane < 16) {
#pragma unroll
      for (int ct = 0; ct < 4; ++ct)
        Xlds[wave*16 + si][16*ct + c] = (_Float16)Xacc[ct];
    }
  }

  __builtin_amdgcn_s_waitcnt(0xC07F);
  __syncthreads();   // cheap insurance; data flow is actually wave-private

  // ================= rho: each wave does its own 16 states =================
  h16x8 R1[4][2], R2[4][2], R3[2][2];
#pragma unroll
  for (int ct = 0; ct < 4; ++ct)
#pragma unroll
    for (int ks = 0; ks < 2; ++ks) {
      h16x8 f1, f2;
#pragma unroll
      for (int j = 0; j < 8; ++j) {
        const int p = 32*ks + 8*q + j;
        const int f = 16*(p & 3) + (p >> 2);
        f1[j] = (_Float16)rW1[p*64 + 16*ct + c];   // X stored unpermuted
        f2[j] = (_Float16)rW2[f*64 + 16*ct + c];   // r1 out stored permuted
      }
      R1[ct][ks] = f1;
      R2[ct][ks] = f2;
    }
#pragma unroll
  for (int ct = 0; ct < 2; ++ct)
#pragma unroll
    for (int ks = 0; ks < 2; ++ks) {
      h16x8 f3;
#pragma unroll
      for (int j = 0; j < 8; ++j) {
        const int p = 32*ks + 8*q + j;
        const int f = 16*(p & 3) + (p >> 2);
        f3[j] = (_Float16)rW3[f*32 + 16*ct + c];   // r2 out stored permuted
      }
      R3[ct][ks] = f3;
    }
  float rb1v[4], rb2v[4], rb3v[2];
#pragma unroll
  for (int ct = 0; ct < 4; ++ct) { rb1v[ct] = rb1[16*ct + c]; rb2v[ct] = rb2[16*ct + c]; }
#pragma unroll
  for (int ct = 0; ct < 2; ++ct) rb3v[ct] = rb3[16*ct + c];

  h16x8 AX[2];
#pragma unroll
  for (int ks = 0; ks < 2; ++ks)
    AX[ks] = *(const h16x8*)&Xlds[16*wave + c][32*ks + 8*q];

  fx4 D1[4];
#pragma unroll
  for (int ct = 0; ct < 4; ++ct) {
    fx4 acc = {0.f,0.f,0.f,0.f};
    acc = mfma16(AX[0], R1[ct][0], acc);
    acc = mfma16(AX[1], R1[ct][1], acc);
    D1[ct] = acc;
  }
#pragma unroll
  for (int r = 0; r < 4; ++r) {
    h16x4 pk;
#pragma unroll
    for (int ct = 0; ct < 4; ++ct)
      pk[ct] = (_Float16)fmaxf(D1[ct][r] + rb1v[ct], 0.f);
    *(h16x4*)&h2T[wave][4*q + r][4*c] = pk;
  }
  __builtin_amdgcn_s_waitcnt(0xC07F);
  __builtin_amdgcn_wave_barrier();
  h16x8 A2r[2];
#pragma unroll
  for (int ks = 0; ks < 2; ++ks)
    A2r[ks] = *(const h16x8*)&h2T[wave][c][32*ks + 8*q];
  __builtin_amdgcn_wave_barrier();

  fx4 D2[4];
#pragma unroll
  for (int ct = 0; ct < 4; ++ct) {
    fx4 acc = {0.f,0.f,0.f,0.f};
    acc = mfma16(A2r[0], R2[ct][0], acc);
    acc = mfma16(A2r[1], R2[ct][1], acc);
    D2[ct] = acc;
  }
#pragma unroll
  for (int r = 0; r < 4; ++r) {
    h16x4 pk;
#pragma unroll
    for (int ct = 0; ct < 4; ++ct)
      pk[ct] = (_Float16)fmaxf(D2[ct][r] + rb2v[ct], 0.f);
    *(h16x4*)&h2T[wave][4*q + r][4*c] = pk;
  }
  __builtin_amdgcn_s_waitcnt(0xC07F);
  __builtin_amdgcn_wave_barrier();
  h16x8 A3r[2];
#pragma unroll
  for (int ks = 0; ks < 2; ++ks)
    A3r[ks] = *(const h16x8*)&h2T[wave][c][32*ks + 8*q];
  __builtin_amdgcn_wave_barrier();

  fx4 D3[2];
#pragma unroll
  for (int ct = 0; ct < 2; ++ct) {
    fx4 acc = {0.f,0.f,0.f,0.f};
    acc = mfma16(A3r[0], R3[ct][0], acc);
    acc = mfma16(A3r[1], R3[ct][1], acc);
    D3[ct] = acc;
  }
  const int srow = sBaseBlock + 16*wave + 4*q;
#pragma unroll
  for (int ct = 0; ct < 2; ++ct)
#pragma unroll
    for (int r = 0; r < 4; ++r)
      out[(size_t)(srow + r)*32 + 16*ct + c] = D3[ct][r] + rb3v[ct];
}

extern "C" void kernel_launch(void* const* d_in, const int* in_sizes, int n_in,
                              void* d_out, int out_size, void* d_ws, size_t ws_size,
                              hipStream_t stream) {
  const float* x   = (const float*)d_in[0];
  const float* vel = (const float*)d_in[1];
  const float* pW1 = (const float*)d_in[2];
  const float* pb1 = (const float*)d_in[3];
  const float* pW2 = (const float*)d_in[4];
  const float* pb2 = (const float*)d_in[5];
  const float* pW3 = (const float*)d_in[6];
  const float* pb3 = (const float*)d_in[7];
  const float* rW1 = (const float*)d_in[8];
  const float* rb1 = (const float*)d_in[9];
  const float* rW2 = (const float*)d_in[10];
  const float* rb2 = (const float*)d_in[11];
  const float* rW3 = (const float*)d_in[12];
  const float* rb3 = (const float*)d_in[13];
  float* out = (float*)d_out;

  const int B = in_sizes[0] / 64;        // x is [B, 64]
  deepset_kernel<<<dim3(B / 64), dim3(256), 0, stream>>>(
      x, vel, pW1, pb1, pW2, pb2, pW3, pb3,
      rW1, rb1, rW2, rb2, rW3, rb3, out);
}

// Round 3
// 136.022 us; speedup vs baseline: 1.3105x; 1.3105x over previous
//
#include <hip/hip_runtime.h>

typedef _Float16 h16x8 __attribute__((ext_vector_type(8)));
typedef _Float16 h16x4 __attribute__((ext_vector_type(4)));
typedef _Float16 h16x2 __attribute__((ext_vector_type(2)));
typedef float    fx4   __attribute__((ext_vector_type(4)));

static __device__ __forceinline__ fx4 mfma16(h16x8 a, h16x8 b, fx4 c) {
  return __builtin_amdgcn_mfma_f32_16x16x32_f16(a, b, c, 0, 0, 0);
}

static __device__ __forceinline__ h16x2 splat2(float v) {
  const _Float16 h = (_Float16)v;
  h16x2 r; r[0] = h; r[1] = h; return r;
}

union ABfrag { h16x2 p[4]; h16x8 v; };

// Algebraic structure (vs round 1): sum-pool commutes with the (linear) phi
// layer 3:  X = W3^T (sum_m relu(h2[m])) + 32*b3  — so the per-obstacle-tile
// LDS transpose + layer-3 MFMAs are gone; the phi loop is barrier-free
// (packed-f16 layer1 -> 8 MFMA -> relu-pool accumulate).
//
// Transpose permutation (C-layout producer -> A-layout consumer):
// writer (lane c, col-tile ct) stores feature f=16*ct+c at position p=4*c+ct
// (one ds_write_b64); consumer's weight rows are loaded with
// f = 16*(p&3)+(p>>2) so the K-order matches (dot products are order-invariant).

__global__ __launch_bounds__(256, 2)
void deepset_kernel(const float* __restrict__ x,   const float* __restrict__ vel,
                    const float* __restrict__ pW1, const float* __restrict__ pb1,
                    const float* __restrict__ pW2, const float* __restrict__ pb2,
                    const float* __restrict__ pW3, const float* __restrict__ pb3,
                    const float* __restrict__ rW1, const float* __restrict__ rb1,
                    const float* __restrict__ rW2, const float* __restrict__ rb2,
                    const float* __restrict__ rW3, const float* __restrict__ rb3,
                    float* __restrict__ out)
{
  // wave-private tiles; stride 72 halves (144 B) keeps 8/16B alignment and
  // breaks the 128B power-of-2 bank stride
  __shared__ __align__(16) _Float16 h2T[4][16][72];
  __shared__ __align__(16) _Float16 Xlds[4][16][72];

  const int tid  = threadIdx.x;
  const int wave = tid >> 6;
  const int lane = tid & 63;
  const int q    = lane >> 4;
  const int c    = lane & 15;

  // ---- packed layer-1 constants: lane's 16 features f = 32*ks + 8*q + 2*t (+1)
  h16x2 wx[2][4], wy[2][4], wvx[2][4], wvy[2][4], bbp[2][4];
#pragma unroll
  for (int ks = 0; ks < 2; ++ks)
#pragma unroll
    for (int t = 0; t < 4; ++t) {
      const int f0 = 32*ks + 8*q + 2*t;
#pragma unroll
      for (int e = 0; e < 2; ++e) {
        wx [ks][t][e] = (_Float16)pW1[      f0 + e];
        wy [ks][t][e] = (_Float16)pW1[ 64 + f0 + e];
        wvx[ks][t][e] = (_Float16)pW1[128 + f0 + e];
        wvy[ks][t][e] = (_Float16)pW1[192 + f0 + e];
        bbp[ks][t][e] = (_Float16)pb1[      f0 + e];
      }
    }

  // ---- phi W2 B-fragments (natural rows): lane holds W2[32ks+8q+j][16ct+c]
  h16x8 B2[4][2];
#pragma unroll
  for (int ct = 0; ct < 4; ++ct)
#pragma unroll
    for (int ks = 0; ks < 2; ++ks) {
      h16x8 f2;
#pragma unroll
      for (int j = 0; j < 8; ++j)
        f2[j] = (_Float16)pW2[(32*ks + 8*q + j)*64 + 16*ct + c];
      B2[ct][ks] = f2;
    }
  float b2v[4];
#pragma unroll
  for (int ct = 0; ct < 4; ++ct) b2v[ct] = pb2[16*ct + c];

  const int sBaseBlock = blockIdx.x * 64;
  const int sBase = sBaseBlock + wave * 16;
  const h16x2 z2 = splat2(0.f);

  // ================= phi + pool: 16 states per wave, barrier-free ===========
  // software-pipelined x/vel fetch: load state si+1 while computing state si
  float4 xo_cur = ((const float4*)x)[(size_t)sBase*16 + c];   // obstacles 2c,2c+1
  float2 v_cur  = *(const float2*)(vel + 2*(size_t)sBase);    // wave-uniform

#pragma unroll 1
  for (int si = 0; si < 16; ++si) {
    float4 xo_nxt;
    float2 v_nxt;
    if (si < 15) {
      xo_nxt = ((const float4*)x)[(size_t)(sBase + si + 1)*16 + c];
      v_nxt  = *(const float2*)(vel + 2*(size_t)(sBase + si + 1));
    }
    // per-state constant part of layer 1 (vel is wave-uniform)
    const h16x2 vxp = splat2(v_cur.x);
    const h16x2 vyp = splat2(v_cur.y);
    h16x2 vbp[2][4];
#pragma unroll
    for (int ks = 0; ks < 2; ++ks)
#pragma unroll
      for (int t = 0; t < 4; ++t)
        vbp[ks][t] = vxp * wvx[ks][t] + vyp * wvy[ks][t] + bbp[ks][t];

    float Xacc[4] = {0.f, 0.f, 0.f, 0.f};
#pragma unroll
    for (int hh = 0; hh < 2; ++hh) {          // obstacle o = 2c + hh
      const h16x2 oxp = splat2(hh ? xo_cur.z : xo_cur.x);
      const h16x2 oyp = splat2(hh ? xo_cur.w : xo_cur.y);
      // layer 1 straight into A-fragment layout (packed f16 math)
      h16x8 A1[2];
#pragma unroll
      for (int ks = 0; ks < 2; ++ks) {
        ABfrag a;
#pragma unroll
        for (int t = 0; t < 4; ++t) {
          const h16x2 h = oxp * wx[ks][t] + oyp * wy[ks][t] + vbp[ks][t];
          a.p[t] = __builtin_elementwise_max(h, z2);
        }
        A1[ks] = a.v;
      }
      // layer 2: 4 col-tiles x K=64
#pragma unroll
      for (int ct = 0; ct < 4; ++ct) {
        fx4 acc = {0.f, 0.f, 0.f, 0.f};
        acc = mfma16(A1[0], B2[ct][0], acc);
        acc = mfma16(A1[1], B2[ct][1], acc);
        // relu(h2+b2) pooled into per-lane partials (rows 4q..4q+3)
#pragma unroll
        for (int r = 0; r < 4; ++r)
          Xacc[ct] += fmaxf(acc[r] + b2v[ct], 0.f);
      }
    }
    // cross-quad reduction once per state; lanes 0..15 hold the full sum
#pragma unroll
    for (int ct = 0; ct < 4; ++ct) {
      float v = Xacc[ct];
      v += __shfl_down(v, 16);
      v += __shfl_down(v, 32);
      if (lane < 16) Xlds[wave][si][16*ct + c] = (_Float16)v;
    }
    xo_cur = xo_nxt;
    v_cur  = v_nxt;
  }

  __builtin_amdgcn_s_waitcnt(0xC07F);          // lgkmcnt(0)
  __builtin_amdgcn_wave_barrier();

  // ============ phi layer 3 (batched over the wave's 16 states) ============
  h16x8 B3[4][2];
#pragma unroll
  for (int ct = 0; ct < 4; ++ct)
#pragma unroll
    for (int ks = 0; ks < 2; ++ks) {
      h16x8 f3;
#pragma unroll
      for (int j = 0; j < 8; ++j)
        f3[j] = (_Float16)pW3[(32*ks + 8*q + j)*64 + 16*ct + c];  // natural rows
      B3[ct][ks] = f3;
    }
  float b3s[4];
#pragma unroll
  for (int ct = 0; ct < 4; ++ct) b3s[ct] = 32.f * pb3[16*ct + c];

  h16x8 AX[2];
#pragma unroll
  for (int ks = 0; ks < 2; ++ks)
    AX[ks] = *(const h16x8*)&Xlds[wave][c][32*ks + 8*q];

  fx4 C3[4];
#pragma unroll
  for (int ct = 0; ct < 4; ++ct) {
    fx4 acc = {0.f,0.f,0.f,0.f};
    acc = mfma16(AX[0], B3[ct][0], acc);
    acc = mfma16(AX[1], B3[ct][1], acc);
    C3[ct] = acc;
  }
  // X (+32*b3, linear) -> permuted transpose write
#pragma unroll
  for (int r = 0; r < 4; ++r) {
    h16x4 pk;
#pragma unroll
    for (int ct = 0; ct < 4; ++ct)
      pk[ct] = (_Float16)(C3[ct][r] + b3s[ct]);
    *(h16x4*)&h2T[wave][4*q + r][4*c] = pk;
  }

  // ================= rho: 16 states per wave =================
  h16x8 R1[4][2], R2[4][2], R3[2][2];
#pragma unroll
  for (int ct = 0; ct < 4; ++ct)
#pragma unroll
    for (int ks = 0; ks < 2; ++ks) {
      h16x8 f1, f2;
#pragma unroll
      for (int j = 0; j < 8; ++j) {
        const int p = 32*ks + 8*q + j;
        const int f = 16*(p & 3) + (p >> 2);       // permuted rows (transposed in)
        f1[j] = (_Float16)rW1[f*64 + 16*ct + c];
        f2[j] = (_Float16)rW2[f*64 + 16*ct + c];
      }
      R1[ct][ks] = f1;
      R2[ct][ks] = f2;
    }
#pragma unroll
  for (int ct = 0; ct < 2; ++ct)
#pragma unroll
    for (int ks = 0; ks < 2; ++ks) {
      h16x8 f3;
#pragma unroll
      for (int j = 0; j < 8; ++j) {
        const int p = 32*ks + 8*q + j;
        const int f = 16*(p & 3) + (p >> 2);
        f3[j] = (_Float16)rW3[f*32 + 16*ct + c];
      }
      R3[ct][ks] = f3;
    }
  float rb1v[4], rb2v[4], rb3v[2];
#pragma unroll
  for (int ct = 0; ct < 4; ++ct) { rb1v[ct] = rb1[16*ct + c]; rb2v[ct] = rb2[16*ct + c]; }
#pragma unroll
  for (int ct = 0; ct < 2; ++ct) rb3v[ct] = rb3[16*ct + c];

  __builtin_amdgcn_s_waitcnt(0xC07F);
  __builtin_amdgcn_wave_barrier();
  h16x8 A1r[2];
#pragma unroll
  for (int ks = 0; ks < 2; ++ks)
    A1r[ks] = *(const h16x8*)&h2T[wave][c][32*ks + 8*q];
  __builtin_amdgcn_wave_barrier();

  fx4 D1[4];
#pragma unroll
  for (int ct = 0; ct < 4; ++ct) {
    fx4 acc = {0.f,0.f,0.f,0.f};
    acc = mfma16(A1r[0], R1[ct][0], acc);
    acc = mfma16(A1r[1], R1[ct][1], acc);
    D1[ct] = acc;
  }
#pragma unroll
  for (int r = 0; r < 4; ++r) {
    h16x4 pk;
#pragma unroll
    for (int ct = 0; ct < 4; ++ct)
      pk[ct] = (_Float16)fmaxf(D1[ct][r] + rb1v[ct], 0.f);
    *(h16x4*)&h2T[wave][4*q + r][4*c] = pk;
  }
  __builtin_amdgcn_s_waitcnt(0xC07F);
  __builtin_amdgcn_wave_barrier();
  h16x8 A2r[2];
#pragma unroll
  for (int ks = 0; ks < 2; ++ks)
    A2r[ks] = *(const h16x8*)&h2T[wave][c][32*ks + 8*q];
  __builtin_amdgcn_wave_barrier();

  fx4 D2[4];
#pragma unroll
  for (int ct = 0; ct < 4; ++ct) {
    fx4 acc = {0.f,0.f,0.f,0.f};
    acc = mfma16(A2r[0], R2[ct][0], acc);
    acc = mfma16(A2r[1], R2[ct][1], acc);
    D2[ct] = acc;
  }
#pragma unroll
  for (int r = 0; r < 4; ++r) {
    h16x4 pk;
#pragma unroll
    for (int ct = 0; ct < 4; ++ct)
      pk[ct] = (_Float16)fmaxf(D2[ct][r] + rb2v[ct], 0.f);
    *(h16x4*)&h2T[wave][4*q + r][4*c] = pk;
  }
  __builtin_amdgcn_s_waitcnt(0xC07F);
  __builtin_amdgcn_wave_barrier();
  h16x8 A3r[2];
#pragma unroll
  for (int ks = 0; ks < 2; ++ks)
    A3r[ks] = *(const h16x8*)&h2T[wave][c][32*ks + 8*q];
  __builtin_amdgcn_wave_barrier();

  fx4 D3[2];
#pragma unroll
  for (int ct = 0; ct < 2; ++ct) {
    fx4 acc = {0.f,0.f,0.f,0.f};
    acc = mfma16(A3r[0], R3[ct][0], acc);
    acc = mfma16(A3r[1], R3[ct][1], acc);
    D3[ct] = acc;
  }
  const int srow = sBaseBlock + 16*wave + 4*q;
#pragma unroll
  for (int ct = 0; ct < 2; ++ct)
#pragma unroll
    for (int r = 0; r < 4; ++r)
      out[(size_t)(srow + r)*32 + 16*ct + c] = D3[ct][r] + rb3v[ct];
}

extern "C" void kernel_launch(void* const* d_in, const int* in_sizes, int n_in,
                              void* d_out, int out_size, void* d_ws, size_t ws_size,
                              hipStream_t stream) {
  const float* x   = (const float*)d_in[0];
  const float* vel = (const float*)d_in[1];
  const float* pW1 = (const float*)d_in[2];
  const float* pb1 = (const float*)d_in[3];
  const float* pW2 = (const float*)d_in[4];
  const float* pb2 = (const float*)d_in[5];
  const float* pW3 = (const float*)d_in[6];
  const float* pb3 = (const float*)d_in[7];
  const float* rW1 = (const float*)d_in[8];
  const float* rb1 = (const float*)d_in[9];
  const float* rW2 = (const float*)d_in[10];
  const float* rb2 = (const float*)d_in[11];
  const float* rW3 = (const float*)d_in[12];
  const float* rb3 = (const float*)d_in[13];
  float* out = (float*)d_out;

  const int B = in_sizes[0] / 64;        // x is [B, 64]
  deepset_kernel<<<dim3(B / 64), dim3(256), 0, stream>>>(
      x, vel, pW1, pb1, pW2, pb2, pW3, pb3,
      rW1, rb1, rW2, rb2, rW3, rb3, out);
}